// Round 5
// baseline (702.522 us; speedup 1.0000x reference)
//
#include <hip/hip_runtime.h>
#include <stdint.h>

typedef unsigned short u16;
typedef __bf16 bf16x8 __attribute__((ext_vector_type(8)));
typedef float f32x4 __attribute__((ext_vector_type(4)));
typedef float f32x16 __attribute__((ext_vector_type(16)));

__device__ __forceinline__ u16 f2b(float f) {
  union { float f; unsigned u; } v; v.f = f;
  unsigned r = v.u + 0x7fffu + ((v.u >> 16) & 1u);
  return (u16)(r >> 16);
}
__device__ __forceinline__ float b2f(u16 b) {
  union { unsigned u; float f; } v; v.u = ((unsigned)b) << 16;
  return v.f;
}

// st-swizzle for 64B-row LDS slots: flips 16B-chunk bits 4-5 with row bits.
__device__ __forceinline__ int swz64(int b) {
  return b ^ (((((b >> 6) & 3) ^ ((b >> 8) & 1))) << 4);
}

#define SB0() __builtin_amdgcn_sched_barrier(0)

// ---------------------------------------------------------------- cast fp32 -> bf16
__global__ __launch_bounds__(256) void cast_bf16(const float* __restrict__ in,
                                                 u16* __restrict__ out, int n4) {
  int i = blockIdx.x * 256 + threadIdx.x;
  if (i >= n4) return;
  float4 f = ((const float4*)in)[i];
  ushort4 r = make_ushort4(f2b(f.x), f2b(f.y), f2b(f.z), f2b(f.w));
  ((ushort4*)out)[i] = r;
}

// ---------------------------------------------------------------- fold fm weight into projection
// out[h*128+j, i] = sum_d fmw[j,d] * W[h*128+d, i]   (bf16 out)
__global__ __launch_bounds__(256) void fold_w(const float* __restrict__ W,
                                              const float* __restrict__ fmw,
                                              u16* __restrict__ out) {
  int hj = blockIdx.x;
  int h = hj >> 7, j = hj & 127;
  int i0 = threadIdx.x * 4;
  float a0 = 0.f, a1 = 0.f, a2 = 0.f, a3 = 0.f;
  const float* Wh = W + (size_t)(h * 128) * 1024 + i0;
  const float* fw = fmw + j * 128;
  for (int d = 0; d < 128; ++d) {
    float wv = fw[d];
    const float* wr = Wh + (size_t)d * 1024;
    a0 += wv * wr[0]; a1 += wv * wr[1]; a2 += wv * wr[2]; a3 += wv * wr[3];
  }
  ushort4 r = make_ushort4(f2b(a0), f2b(a1), f2b(a2), f2b(a3));
  ((ushort4*)(out + (size_t)hj * 1024))[threadIdx.x] = r;
}

// ---------------------------------------------------------------- 256x256 8-phase BT GEMM
// C[M,N] = A[M,K] @ B[N,K]^T, A/B bf16. OUT_BF16 ? bf16 C : fp32 C.
// 512 threads = 8 waves (2M x 4N). LDS 128 KiB double-buffered, counted vmcnt.
template <int OUT_BF16>
__global__ __launch_bounds__(512, 2) void gemm256(const u16* __restrict__ A,
                                                  const u16* __restrict__ B,
                                                  void* __restrict__ Cv,
                                                  int M, int N, int K, int LNT) {
  __shared__ u16 lds[65536];  // 128 KiB
  const int tid = threadIdx.x, w = tid >> 6, lane = tid & 63;
  int g = blockIdx.x;
  int wg = (g & 7) * ((int)gridDim.x >> 3) + (g >> 3);  // XCD swizzle (nwg%8==0)
  const int nt = wg & ((1 << LNT) - 1), mt = wg >> LNT;
  const int m0 = mt << 8, n0 = nt << 8;
  const int wm = w >> 2, wn = w & 3;
  const int fm = lane & 15, fkb = (lane >> 4) << 4;  // frag row, k byte offset

  int so0 = w * 1024 + lane * 16;
  int so1 = so0 + 8192;
  const int p0s = swz64(so0), p1s = swz64(so1);
  const size_t ga0 = (size_t)(p0s >> 6) * K + ((p0s & 63) >> 1);
  const size_t ga1 = (size_t)(p1s >> 6) * K + ((p1s & 63) >> 1);
  so0 >>= 1; so1 >>= 1;  // u16 offsets
#define STAGE(g0, slot)                                                               \
  do {                                                                                \
    __builtin_amdgcn_global_load_lds(                                                 \
        (const __attribute__((address_space(1))) unsigned int*)((g0) + ga0),          \
        (__attribute__((address_space(3))) unsigned int*)((slot) + so0), 16, 0, 0);   \
    __builtin_amdgcn_global_load_lds(                                                 \
        (const __attribute__((address_space(1))) unsigned int*)((g0) + ga1),          \
        (__attribute__((address_space(3))) unsigned int*)((slot) + so1), 16, 0, 0);   \
  } while (0)

  int aoff[2][4], boff[4];
#pragma unroll
  for (int mh = 0; mh < 2; ++mh)
#pragma unroll
    for (int mi = 0; mi < 4; ++mi)
      aoff[mh][mi] = swz64((wm * 128 + mh * 64 + mi * 16 + fm) * 64 + fkb) >> 1;
#pragma unroll
  for (int ni = 0; ni < 4; ++ni)
    boff[ni] = swz64((wn * 64 + ni * 16 + fm) * 64 + fkb) >> 1;

  const u16* Ag = A + (size_t)m0 * K;
  const u16* Bg = B + (size_t)n0 * K;
  const int NT = K >> 6;
  f32x4 acc[8][4] = {};

  STAGE(Ag, lds);
  STAGE(Bg, lds + 32768);
  STAGE(Ag + 32, lds + 8192);
  STAGE(Bg + 32, lds + 32768 + 8192);
  STAGE(Ag + 64, lds + 16384);
  STAGE(Bg + 64, lds + 32768 + 16384);
  asm volatile("s_waitcnt vmcnt(4)" ::: "memory");
  __builtin_amdgcn_s_barrier();

  for (int t = 0; t < NT; ++t) {
    const int buf = t & 1, nb = buf ^ 1;
    const u16* As0 = lds + buf * 16384;
    const u16* As1 = As0 + 8192;
    const u16* Bs0 = lds + 32768 + buf * 16384;
    const u16* Bs1 = Bs0 + 8192;
    bf16x8 a[4], bfr[4];

    // ---- phase 0: (mh0, kk0)
#pragma unroll
    for (int mi = 0; mi < 4; ++mi) a[mi] = *(const bf16x8*)(As0 + aoff[0][mi]);
#pragma unroll
    for (int ni = 0; ni < 4; ++ni) bfr[ni] = *(const bf16x8*)(Bs0 + boff[ni]);
    if (t + 1 < NT) STAGE(Ag + (t + 1) * 64 + 32, lds + nb * 16384 + 8192);
    __builtin_amdgcn_s_barrier();
    asm volatile("s_waitcnt lgkmcnt(0)" ::: "memory");
    SB0();
    __builtin_amdgcn_s_setprio(1);
#pragma unroll
    for (int mi = 0; mi < 4; ++mi)
#pragma unroll
      for (int ni = 0; ni < 4; ++ni)
        acc[mi][ni] = __builtin_amdgcn_mfma_f32_16x16x32_bf16(a[mi], bfr[ni], acc[mi][ni], 0, 0, 0);
    __builtin_amdgcn_s_setprio(0);
    __builtin_amdgcn_s_barrier();

    // ---- phase 1: (mh1, kk0)
#pragma unroll
    for (int mi = 0; mi < 4; ++mi) a[mi] = *(const bf16x8*)(As0 + aoff[1][mi]);
    if (t + 1 < NT) STAGE(Bg + (t + 1) * 64 + 32, lds + 32768 + nb * 16384 + 8192);
    __builtin_amdgcn_s_barrier();
    asm volatile("s_waitcnt lgkmcnt(0)" ::: "memory");
    SB0();
    __builtin_amdgcn_s_setprio(1);
#pragma unroll
    for (int mi = 0; mi < 4; ++mi)
#pragma unroll
      for (int ni = 0; ni < 4; ++ni)
        acc[4 + mi][ni] =
            __builtin_amdgcn_mfma_f32_16x16x32_bf16(a[mi], bfr[ni], acc[4 + mi][ni], 0, 0, 0);
    __builtin_amdgcn_s_setprio(0);
    __builtin_amdgcn_s_barrier();

    // ---- phase 2: (mh0, kk1)
#pragma unroll
    for (int mi = 0; mi < 4; ++mi) a[mi] = *(const bf16x8*)(As1 + aoff[0][mi]);
#pragma unroll
    for (int ni = 0; ni < 4; ++ni) bfr[ni] = *(const bf16x8*)(Bs1 + boff[ni]);
    if (t + 2 < NT) STAGE(Ag + (t + 2) * 64, lds + buf * 16384);
    __builtin_amdgcn_s_barrier();
    asm volatile("s_waitcnt lgkmcnt(0)" ::: "memory");
    SB0();
    __builtin_amdgcn_s_setprio(1);
#pragma unroll
    for (int mi = 0; mi < 4; ++mi)
#pragma unroll
      for (int ni = 0; ni < 4; ++ni)
        acc[mi][ni] = __builtin_amdgcn_mfma_f32_16x16x32_bf16(a[mi], bfr[ni], acc[mi][ni], 0, 0, 0);
    __builtin_amdgcn_s_setprio(0);
    __builtin_amdgcn_s_barrier();

    // ---- phase 3: (mh1, kk1)
#pragma unroll
    for (int mi = 0; mi < 4; ++mi) a[mi] = *(const bf16x8*)(As1 + aoff[1][mi]);
    if (t + 2 < NT) STAGE(Bg + (t + 2) * 64, lds + 32768 + buf * 16384);
    __builtin_amdgcn_s_barrier();
    asm volatile("s_waitcnt lgkmcnt(0)" ::: "memory");
    SB0();
    __builtin_amdgcn_s_setprio(1);
#pragma unroll
    for (int mi = 0; mi < 4; ++mi)
#pragma unroll
      for (int ni = 0; ni < 4; ++ni)
        acc[4 + mi][ni] =
            __builtin_amdgcn_mfma_f32_16x16x32_bf16(a[mi], bfr[ni], acc[4 + mi][ni], 0, 0, 0);
    __builtin_amdgcn_s_setprio(0);
    if (t < NT - 2)
      asm volatile("s_waitcnt vmcnt(4)" ::: "memory");
    else
      asm volatile("s_waitcnt vmcnt(0)" ::: "memory");
    __builtin_amdgcn_s_barrier();
  }
#undef STAGE

  const int cr = (lane >> 4) << 2, cc = lane & 15;
  if (OUT_BF16) {
    // ---- epilogue: stage C tile in LDS (256x256 u16 = full 128 KiB)
    u16* Cs = lds;
    u16* Cg = (u16*)Cv;
#pragma unroll
    for (int am = 0; am < 8; ++am)
#pragma unroll
      for (int ni = 0; ni < 4; ++ni)
#pragma unroll
        for (int r = 0; r < 4; ++r)
          Cs[(wm * 128 + (am >> 2) * 64 + (am & 3) * 16 + cr + r) * 256 + wn * 64 + ni * 16 + cc] =
              f2b(acc[am][ni][r]);
    __syncthreads();
#pragma unroll
    for (int pass = 0; pass < 16; ++pass) {
      int row = pass * 16 + (tid >> 5);
      int colb = (tid & 31) << 4;
      *(uint4*)((char*)(Cg + (size_t)(m0 + row) * N + n0) + colb) =
          *(const uint4*)((const char*)(Cs + row * 256) + colb);
    }
  } else {
    // ---- fp32 epilogue: two 128-row half passes; Csf[128][256] f32 = 128 KiB
    float* Csf = (float*)lds;
    float* Cg = (float*)Cv;
#pragma unroll
    for (int hh = 0; hh < 2; ++hh) {
      __syncthreads();
      if (wm == hh) {
#pragma unroll
        for (int am = 0; am < 8; ++am)
#pragma unroll
          for (int ni = 0; ni < 4; ++ni)
#pragma unroll
            for (int r = 0; r < 4; ++r)
              Csf[((am >> 2) * 64 + (am & 3) * 16 + cr + r) * 256 + wn * 64 + ni * 16 + cc] =
                  acc[am][ni][r];
      }
      __syncthreads();
#pragma unroll
      for (int it = 0; it < 16; ++it) {
        int row = it * 8 + (tid >> 6);
        int colb = (tid & 63) << 2;  // 64 float4 per row
        *(float4*)(Cg + (size_t)(m0 + hh * 128 + row) * N + n0 + colb) =
            *(const float4*)(Csf + row * 256 + colb);
      }
    }
  }
}

// ---------------------------------------------------------------- hedgehog softmax
__global__ __launch_bounds__(256) void hedgehog_sm(const u16* __restrict__ y,
                                                   const float* __restrict__ bias,
                                                   u16* __restrict__ phi, float scale,
                                                   int colbase) {
  int wave = threadIdx.x >> 6, lane = threadIdx.x & 63;
  int rh = blockIdx.x * 4 + wave;
  const u16* yr = y + (size_t)(rh >> 3) * 2048 + colbase + (rh & 7) * 128;
  float a1 = 2.f * (b2f(yr[lane]) + bias[lane]);
  float a2 = 2.f * (b2f(yr[lane + 64]) + bias[lane + 64]);
  float mx = fmaxf(fabsf(a1), fabsf(a2));
#pragma unroll
  for (int off = 32; off; off >>= 1) mx = fmaxf(mx, __shfl_xor(mx, off, 64));
  float e1 = __expf(a1 - mx), e2 = __expf(a2 - mx);
  float n1 = __expf(-a1 - mx), n2 = __expf(-a2 - mx);
  float s = e1 + e2 + n1 + n2;
#pragma unroll
  for (int off = 32; off; off >>= 1) s += __shfl_xor(s, off, 64);
  float inv = scale / s;
  u16* pr = phi + (size_t)rh * 256;
  pr[lane] = f2b(e1 * inv);
  pr[lane + 64] = f2b(e2 * inv);
  pr[lane + 128] = f2b(n1 * inv);
  pr[lane + 192] = f2b(n2 * inv);
}

// ---------------------------------------------------------------- attention: per-chunk KV, C=64
// block g: chunk n = g&127, head h = g>>7. KV[vc][d] = sum_t' vT[vc][t'] k[t'][d].
// Kt staged [256][72] (r4-proven); no o write, no q read.
__global__ __launch_bounds__(256, 1) void attn_kv64(const u16* __restrict__ phi_k,
                                                    const u16* __restrict__ vt,
                                                    u16* __restrict__ kv) {
  __shared__ u16 Kt[18432];  // [256][72]
  int g = blockIdx.x;
  int n = g & 127, h = g >> 7;
  int t0 = n * 64;
  const u16* kg = phi_k + ((size_t)t0 * 8 + h) * 256;  // row stride 2048
  const u16* vg = vt + (size_t)(h * 128) * 8192 + t0;  // vc rows, stride 8192
  int tid = threadIdx.x, lane = tid & 63, w = tid >> 6;
  const int fr = lane & 31, fg = (lane >> 5) << 3;
  const int rbase = (lane >> 5) << 2;

  // ---- Kt[d 0..255][t' 0..63] from global k (stride 72)
  {
    int r4 = (tid & 15) << 2;
    int d0 = (tid >> 4) << 4;
    u16 tmp[4][16];
#pragma unroll
    for (int r = 0; r < 4; ++r) {
      const u16* src = kg + (size_t)(r4 + r) * 2048 + d0;
      *(uint4*)(tmp[r]) = *(const uint4*)src;
      *(uint4*)(tmp[r] + 8) = *(const uint4*)(src + 8);
    }
#pragma unroll
    for (int jj = 0; jj < 16; ++jj) {
      ushort4 pk = make_ushort4(tmp[0][jj], tmp[1][jj], tmp[2][jj], tmp[3][jj]);
      *(ushort4*)(Kt + (d0 + jj) * 72 + r4) = pk;
    }
  }
  __syncthreads();
  const int nd = w << 6;  // wave owns d in [nd, nd+64)
  f32x16 accKV[4][2] = {};
#pragma unroll
  for (int ks = 0; ks < 4; ++ks) {
    bf16x8 a[4], b[2];
#pragma unroll
    for (int mi = 0; mi < 4; ++mi)
      a[mi] = *(const bf16x8*)(vg + (size_t)(mi * 32 + fr) * 8192 + ks * 16 + fg);
#pragma unroll
    for (int nj = 0; nj < 2; ++nj)
      b[nj] = *(const bf16x8*)(Kt + (nd + nj * 32 + fr) * 72 + ks * 16 + fg);
#pragma unroll
    for (int mi = 0; mi < 4; ++mi)
#pragma unroll
      for (int nj = 0; nj < 2; ++nj)
        accKV[mi][nj] =
            __builtin_amdgcn_mfma_f32_32x32x16_bf16(a[mi], b[nj], accKV[mi][nj], 0, 0, 0);
  }
  {
    u16* kvg = kv + (size_t)g * 32768;
#pragma unroll
    for (int mi = 0; mi < 4; ++mi)
#pragma unroll
      for (int nj = 0; nj < 2; ++nj) {
        f32x16 acc = accKV[mi][nj];
        int d = nd + nj * 32 + (lane & 31);
#pragma unroll
        for (int r = 0; r < 16; ++r) {
          int vc = mi * 32 + (r & 3) + ((r >> 2) << 3) + rbase;
          kvg[(size_t)vc * 256 + d] = f2b(acc[r]);
        }
      }
  }
}

// ---------------------------------------------------------------- attention phase B, C=64
// in-place exclusive prefix over 128 chunk-KVs per h; 4 bf16/thread, fp32 carry.
__global__ __launch_bounds__(256) void kv_scan64(u16* __restrict__ kv) {
  int idx = blockIdx.x * 256 + threadIdx.x;  // 0..65535
  int h = idx >> 13;                         // 8192 lanes per h
  int e4 = idx & 8191;
  u16* p = kv + (size_t)h * 4194304 + (size_t)e4 * 4;
  float run[4] = {};
#pragma unroll 4
  for (int nn = 0; nn < 128; ++nn) {
    uint2 raw = *(const uint2*)p;
    u16* rv = (u16*)&raw;
    uint2 outw;
    u16* ov = (u16*)&outw;
#pragma unroll
    for (int i = 0; i < 4; ++i) {
      float v = b2f(rv[i]);
      ov[i] = f2b(run[i]);
      run[i] += v;
    }
    *(uint2*)p = outw;
    p += 32768;
  }
}

// ---------------------------------------------------------------- attention fused o, C=64
// block g: chunk n = g&127, head h = g>>7. scores=q@k^T (64x64, mask) -> At LDS;
// o = At@vT + q@S (same accumulator), single fp32 write (no RMW).
__global__ __launch_bounds__(256, 1) void attn_fused64(const u16* __restrict__ phi_q,
                                                       const u16* __restrict__ phi_k,
                                                       const u16* __restrict__ vt,
                                                       const u16* __restrict__ kv,
                                                       float* __restrict__ o) {
  __shared__ u16 At[8704];  // [64][136]
  int g = blockIdx.x;
  int n = g & 127, h = g >> 7;
  int t0 = n * 64;
  const u16* qg = phi_q + ((size_t)t0 * 8 + h) * 256;  // row stride 2048
  const u16* kg = phi_k + ((size_t)t0 * 8 + h) * 256;
  const u16* vg = vt + (size_t)(h * 128) * 8192 + t0;  // vc rows, stride 8192
  const u16* sg = kv + (size_t)g * 32768;              // S[vc][d], stride 256
  int tid = threadIdx.x, lane = tid & 63, w = tid >> 6;
  const int fr = lane & 31, fg = (lane >> 5) << 3;
  const int rbase = (lane >> 5) << 2;
  const int mw = (w >> 1) << 5;  // t tile (0/32)
  const int nw = (w & 1) << 5;   // t' tile (0/32)
  const int nv = (w & 1) << 6;   // vc half (0/64)

  // ---- scores (64x64, one 32x32 tile per wave)
  f32x16 accS = {};
#pragma unroll
  for (int ks = 0; ks < 16; ++ks) {
    bf16x8 a = *(const bf16x8*)(qg + (size_t)(mw + fr) * 2048 + ks * 16 + fg);
    bf16x8 b = *(const bf16x8*)(kg + (size_t)(nw + fr) * 2048 + ks * 16 + fg);
    accS = __builtin_amdgcn_mfma_f32_32x32x16_bf16(a, b, accS, 0, 0, 0);
  }
  // ---- mask + At (causal incl diagonal)
  {
    int col = nw + (lane & 31);
#pragma unroll
    for (int r = 0; r < 16; ++r) {
      int row = mw + (r & 3) + ((r >> 2) << 3) + rbase;
      At[row * 136 + col] = f2b(col <= row ? accS[r] : 0.f);
    }
  }
  __syncthreads();
  // ---- o = At @ vT + q @ S : wave -> rows [mw,mw+32) x vc [nv,nv+64)
  f32x16 accO[2] = {};
#pragma unroll
  for (int ks = 0; ks < 4; ++ks) {
    bf16x8 a = *(const bf16x8*)(At + (mw + fr) * 136 + ks * 16 + fg);
#pragma unroll
    for (int nj = 0; nj < 2; ++nj) {
      bf16x8 b = *(const bf16x8*)(vg + (size_t)(nv + nj * 32 + fr) * 8192 + ks * 16 + fg);
      accO[nj] = __builtin_amdgcn_mfma_f32_32x32x16_bf16(a, b, accO[nj], 0, 0, 0);
    }
  }
#pragma unroll
  for (int ks = 0; ks < 16; ++ks) {
    bf16x8 a = *(const bf16x8*)(qg + (size_t)(mw + fr) * 2048 + ks * 16 + fg);
#pragma unroll
    for (int nj = 0; nj < 2; ++nj) {
      bf16x8 b = *(const bf16x8*)(sg + (size_t)(nv + nj * 32 + fr) * 256 + ks * 16 + fg);
      accO[nj] = __builtin_amdgcn_mfma_f32_32x32x16_bf16(a, b, accO[nj], 0, 0, 0);
    }
  }
  {
    float* og = o + ((size_t)t0 * 8 + h) * 128;  // row stride 1024
#pragma unroll
    for (int nj = 0; nj < 2; ++nj) {
      int vc = nv + nj * 32 + (lane & 31);
#pragma unroll
      for (int r = 0; r < 16; ++r) {
        int row = mw + (r & 3) + ((r >> 2) << 3) + rbase;
        og[(size_t)row * 1024 + vc] = accO[nj][r];
      }
    }
  }
}

// ---------------------------------------------------------------- rmsnorm (per 1024-dim row)
__global__ __launch_bounds__(256) void rmsnorm_k(const float* __restrict__ o,
                                                 u16* __restrict__ on) {
  __shared__ float red[4];
  int row = blockIdx.x;
  const float* orow = o + (size_t)row * 1024;
  int tid = threadIdx.x;
  float4 v = ((const float4*)orow)[tid];
  float ss = v.x * v.x + v.y * v.y + v.z * v.z + v.w * v.w;
#pragma unroll
  for (int off = 32; off; off >>= 1) ss += __shfl_xor(ss, off, 64);
  if ((tid & 63) == 0) red[tid >> 6] = ss;
  __syncthreads();
  float tot = red[0] + red[1] + red[2] + red[3];
  float rms = rsqrtf(tot * (1.f / 1024.f) + 1e-5f);
  ushort4 r = make_ushort4(f2b(v.x * rms), f2b(v.y * rms), f2b(v.z * rms), f2b(v.w * rms));
  ((ushort4*)(on + (size_t)row * 1024))[tid] = r;
}

// ---------------------------------------------------------------- launch
extern "C" void kernel_launch(void* const* d_in, const int* in_sizes, int n_in,
                              void* d_out, int out_size, void* d_ws, size_t ws_size,
                              hipStream_t stream) {
  const float* x     = (const float*)d_in[0];
  const float* Wq    = (const float*)d_in[1];
  const float* Wk    = (const float*)d_in[2];
  const float* Wv    = (const float*)d_in[3];
  const float* Wo    = (const float*)d_in[4];
  const float* fmq_w = (const float*)d_in[5];
  const float* fmq_b = (const float*)d_in[6];
  const float* fmk_w = (const float*)d_in[7];
  const float* fmk_b = (const float*)d_in[8];

  // Workspace 184 MiB. kvb 64 MiB [0,64MiB) aliases xb[0,16), yb[16,48), onb[48,64).
  // Temporal safety (stream-ordered, per batch): xb dead after vT GEMM (precedes
  // attn_kv64's kv write); yb dead after hedgehog; onb only live rmsnorm->out-GEMM,
  // during which kv is dead (attn_fused64 consumed it); next batch's kv write comes
  // after this batch's out-GEMM.
  char* ws = (char*)d_ws;
  u16*   kvb  = (u16*)(ws + 0);            // 64 MiB (128 chunks x 8 h x 64 KiB)
  u16*   xb   = (u16*)(ws + 0);            // 16 MiB
  u16*   yb   = (u16*)(ws + 16777216);     // 32 MiB (merged q|k, [8192][2048])
  u16*   onb  = (u16*)(ws + 50331648);     // 16 MiB
  u16*   phiq = (u16*)(ws + 67108864);     // 32 MiB
  u16*   phik = (u16*)(ws + 100663296);    // 32 MiB
  u16*   vtb  = (u16*)(ws + 134217728);    // 16 MiB ([1024 vc-rows][8192 t])
  float* obuf = (float*)(ws + 150994944);  // 32 MiB
  u16*   wqkc = (u16*)(ws + 184549376);    // 4 MiB ([2048][1024]: q rows | k rows)
  u16*   wvb  = (u16*)(ws + 188743680);    // 2 MiB
  u16*   wob  = (u16*)(ws + 190840832);    // 2 MiB -> end 192937984 (184 MiB)

  // weight prep (once)
  cast_bf16<<<1024, 256, 0, stream>>>(Wv, wvb, 262144);
  cast_bf16<<<1024, 256, 0, stream>>>(Wo, wob, 262144);
  fold_w<<<1024, 256, 0, stream>>>(Wq, fmq_w, wqkc);
  fold_w<<<1024, 256, 0, stream>>>(Wk, fmk_w, wqkc + 1048576);

  for (int b = 0; b < 2; ++b) {
    const float* xsrc = x + (size_t)b * 8388608;
    float* osrc = (float*)d_out + (size_t)b * 8388608;
    cast_bf16<<<8192, 256, 0, stream>>>(xsrc, xb, 2097152);
    // merged q|k projection: [8192][2048] — 32x8 tiles
    gemm256<1><<<256, 512, 0, stream>>>(xb, wqkc, yb, 8192, 2048, 1024, 3);
    hedgehog_sm<<<16384, 256, 0, stream>>>(yb, fmq_b, phiq, 0.0625f, 0);     // 256^-0.5
    hedgehog_sm<<<16384, 256, 0, stream>>>(yb, fmk_b, phik, 1.0f, 1024);
    // v^T: C[1024][8192] = Wv @ x^T — 4x32 tiles
    gemm256<1><<<128, 512, 0, stream>>>(wvb, xb, vtb, 1024, 8192, 1024, 5);
    // attention, C=64: KV -> exclusive scan -> fused (intra + inter) o
    attn_kv64<<<1024, 256, 0, stream>>>(phik, vtb, kvb);
    kv_scan64<<<256, 256, 0, stream>>>(kvb);
    attn_fused64<<<1024, 256, 0, stream>>>(phiq, phik, vtb, kvb, obuf);
    // rmsnorm + output projection (fp32 out) — 32x4 tiles
    rmsnorm_k<<<8192, 256, 0, stream>>>(obuf, onb);
    gemm256<0><<<128, 512, 0, stream>>>(onb, wob, osrc, 8192, 1024, 1024, 2);
  }
}

// Round 6
// 643.352 us; speedup vs baseline: 1.0920x; 1.0920x over previous
//
#include <hip/hip_runtime.h>
#include <stdint.h>

typedef unsigned short u16;
typedef __bf16 bf16x8 __attribute__((ext_vector_type(8)));
typedef float f32x4 __attribute__((ext_vector_type(4)));
typedef float f32x16 __attribute__((ext_vector_type(16)));

__device__ __forceinline__ u16 f2b(float f) {
  union { float f; unsigned u; } v; v.f = f;
  unsigned r = v.u + 0x7fffu + ((v.u >> 16) & 1u);
  return (u16)(r >> 16);
}
__device__ __forceinline__ float b2f(u16 b) {
  union { unsigned u; float f; } v; v.u = ((unsigned)b) << 16;
  return v.f;
}

// st-swizzle for 64B-row LDS slots: flips 16B-chunk bits 4-5 with row bits.
__device__ __forceinline__ int swz64(int b) {
  return b ^ (((((b >> 6) & 3) ^ ((b >> 8) & 1))) << 4);
}

#define SB0() __builtin_amdgcn_sched_barrier(0)

// ---------------------------------------------------------------- cast fp32 -> bf16
__global__ __launch_bounds__(256) void cast_bf16(const float* __restrict__ in,
                                                 u16* __restrict__ out, int n4) {
  int i = blockIdx.x * 256 + threadIdx.x;
  if (i >= n4) return;
  float4 f = ((const float4*)in)[i];
  ushort4 r = make_ushort4(f2b(f.x), f2b(f.y), f2b(f.z), f2b(f.w));
  ((ushort4*)out)[i] = r;
}

// ---------------------------------------------------------------- fold fm weight into projection
// out[h*128+j, i] = sum_d fmw[j,d] * W[h*128+d, i]   (bf16 out)
__global__ __launch_bounds__(256) void fold_w(const float* __restrict__ W,
                                              const float* __restrict__ fmw,
                                              u16* __restrict__ out) {
  int hj = blockIdx.x;
  int h = hj >> 7, j = hj & 127;
  int i0 = threadIdx.x * 4;
  float a0 = 0.f, a1 = 0.f, a2 = 0.f, a3 = 0.f;
  const float* Wh = W + (size_t)(h * 128) * 1024 + i0;
  const float* fw = fmw + j * 128;
  for (int d = 0; d < 128; ++d) {
    float wv = fw[d];
    const float* wr = Wh + (size_t)d * 1024;
    a0 += wv * wr[0]; a1 += wv * wr[1]; a2 += wv * wr[2]; a3 += wv * wr[3];
  }
  ushort4 r = make_ushort4(f2b(a0), f2b(a1), f2b(a2), f2b(a3));
  ((ushort4*)(out + (size_t)hj * 1024))[threadIdx.x] = r;
}

// ---------------------------------------------------------------- 256x256 8-phase BT GEMM
// C[M,N] = A[M,K] @ B[N,K]^T, all bf16. 512 threads = 8 waves (2M x 4N).
// LDS 128 KiB double-buffered, counted vmcnt. Used for the q|k GEMM (256 blocks).
__global__ __launch_bounds__(512, 2) void gemm256(const u16* __restrict__ A,
                                                  const u16* __restrict__ B,
                                                  u16* __restrict__ C,
                                                  int M, int N, int K, int LNT) {
  __shared__ u16 lds[65536];  // 128 KiB
  const int tid = threadIdx.x, w = tid >> 6, lane = tid & 63;
  int g = blockIdx.x;
  int wg = (g & 7) * ((int)gridDim.x >> 3) + (g >> 3);  // XCD swizzle (nwg%8==0)
  const int nt = wg & ((1 << LNT) - 1), mt = wg >> LNT;
  const int m0 = mt << 8, n0 = nt << 8;
  const int wm = w >> 2, wn = w & 3;
  const int fm = lane & 15, fkb = (lane >> 4) << 4;  // frag row, k byte offset

  int so0 = w * 1024 + lane * 16;
  int so1 = so0 + 8192;
  const int p0s = swz64(so0), p1s = swz64(so1);
  const size_t ga0 = (size_t)(p0s >> 6) * K + ((p0s & 63) >> 1);
  const size_t ga1 = (size_t)(p1s >> 6) * K + ((p1s & 63) >> 1);
  so0 >>= 1; so1 >>= 1;  // u16 offsets
#define STAGE(g0, slot)                                                               \
  do {                                                                                \
    __builtin_amdgcn_global_load_lds(                                                 \
        (const __attribute__((address_space(1))) unsigned int*)((g0) + ga0),          \
        (__attribute__((address_space(3))) unsigned int*)((slot) + so0), 16, 0, 0);   \
    __builtin_amdgcn_global_load_lds(                                                 \
        (const __attribute__((address_space(1))) unsigned int*)((g0) + ga1),          \
        (__attribute__((address_space(3))) unsigned int*)((slot) + so1), 16, 0, 0);   \
  } while (0)

  int aoff[2][4], boff[4];
#pragma unroll
  for (int mh = 0; mh < 2; ++mh)
#pragma unroll
    for (int mi = 0; mi < 4; ++mi)
      aoff[mh][mi] = swz64((wm * 128 + mh * 64 + mi * 16 + fm) * 64 + fkb) >> 1;
#pragma unroll
  for (int ni = 0; ni < 4; ++ni)
    boff[ni] = swz64((wn * 64 + ni * 16 + fm) * 64 + fkb) >> 1;

  const u16* Ag = A + (size_t)m0 * K;
  const u16* Bg = B + (size_t)n0 * K;
  const int NT = K >> 6;
  f32x4 acc[8][4] = {};

  STAGE(Ag, lds);
  STAGE(Bg, lds + 32768);
  STAGE(Ag + 32, lds + 8192);
  STAGE(Bg + 32, lds + 32768 + 8192);
  STAGE(Ag + 64, lds + 16384);
  STAGE(Bg + 64, lds + 32768 + 16384);
  asm volatile("s_waitcnt vmcnt(4)" ::: "memory");
  __builtin_amdgcn_s_barrier();

  for (int t = 0; t < NT; ++t) {
    const int buf = t & 1, nb = buf ^ 1;
    const u16* As0 = lds + buf * 16384;
    const u16* As1 = As0 + 8192;
    const u16* Bs0 = lds + 32768 + buf * 16384;
    const u16* Bs1 = Bs0 + 8192;
    bf16x8 a[4], bfr[4];

    // ---- phase 0: (mh0, kk0)
#pragma unroll
    for (int mi = 0; mi < 4; ++mi) a[mi] = *(const bf16x8*)(As0 + aoff[0][mi]);
#pragma unroll
    for (int ni = 0; ni < 4; ++ni) bfr[ni] = *(const bf16x8*)(Bs0 + boff[ni]);
    if (t + 1 < NT) STAGE(Ag + (t + 1) * 64 + 32, lds + nb * 16384 + 8192);
    __builtin_amdgcn_s_barrier();
    asm volatile("s_waitcnt lgkmcnt(0)" ::: "memory");
    SB0();
    __builtin_amdgcn_s_setprio(1);
#pragma unroll
    for (int mi = 0; mi < 4; ++mi)
#pragma unroll
      for (int ni = 0; ni < 4; ++ni)
        acc[mi][ni] = __builtin_amdgcn_mfma_f32_16x16x32_bf16(a[mi], bfr[ni], acc[mi][ni], 0, 0, 0);
    __builtin_amdgcn_s_setprio(0);
    __builtin_amdgcn_s_barrier();

    // ---- phase 1: (mh1, kk0)
#pragma unroll
    for (int mi = 0; mi < 4; ++mi) a[mi] = *(const bf16x8*)(As0 + aoff[1][mi]);
    if (t + 1 < NT) STAGE(Bg + (t + 1) * 64 + 32, lds + 32768 + nb * 16384 + 8192);
    __builtin_amdgcn_s_barrier();
    asm volatile("s_waitcnt lgkmcnt(0)" ::: "memory");
    SB0();
    __builtin_amdgcn_s_setprio(1);
#pragma unroll
    for (int mi = 0; mi < 4; ++mi)
#pragma unroll
      for (int ni = 0; ni < 4; ++ni)
        acc[4 + mi][ni] =
            __builtin_amdgcn_mfma_f32_16x16x32_bf16(a[mi], bfr[ni], acc[4 + mi][ni], 0, 0, 0);
    __builtin_amdgcn_s_setprio(0);
    __builtin_amdgcn_s_barrier();

    // ---- phase 2: (mh0, kk1)
#pragma unroll
    for (int mi = 0; mi < 4; ++mi) a[mi] = *(const bf16x8*)(As1 + aoff[0][mi]);
#pragma unroll
    for (int ni = 0; ni < 4; ++ni) bfr[ni] = *(const bf16x8*)(Bs1 + boff[ni]);
    if (t + 2 < NT) STAGE(Ag + (t + 2) * 64, lds + buf * 16384);
    __builtin_amdgcn_s_barrier();
    asm volatile("s_waitcnt lgkmcnt(0)" ::: "memory");
    SB0();
    __builtin_amdgcn_s_setprio(1);
#pragma unroll
    for (int mi = 0; mi < 4; ++mi)
#pragma unroll
      for (int ni = 0; ni < 4; ++ni)
        acc[mi][ni] = __builtin_amdgcn_mfma_f32_16x16x32_bf16(a[mi], bfr[ni], acc[mi][ni], 0, 0, 0);
    __builtin_amdgcn_s_setprio(0);
    __builtin_amdgcn_s_barrier();

    // ---- phase 3: (mh1, kk1)
#pragma unroll
    for (int mi = 0; mi < 4; ++mi) a[mi] = *(const bf16x8*)(As1 + aoff[1][mi]);
    if (t + 2 < NT) STAGE(Bg + (t + 2) * 64, lds + 32768 + buf * 16384);
    __builtin_amdgcn_s_barrier();
    asm volatile("s_waitcnt lgkmcnt(0)" ::: "memory");
    SB0();
    __builtin_amdgcn_s_setprio(1);
#pragma unroll
    for (int mi = 0; mi < 4; ++mi)
#pragma unroll
      for (int ni = 0; ni < 4; ++ni)
        acc[4 + mi][ni] =
            __builtin_amdgcn_mfma_f32_16x16x32_bf16(a[mi], bfr[ni], acc[4 + mi][ni], 0, 0, 0);
    __builtin_amdgcn_s_setprio(0);
    if (t < NT - 2)
      asm volatile("s_waitcnt vmcnt(4)" ::: "memory");
    else
      asm volatile("s_waitcnt vmcnt(0)" ::: "memory");
    __builtin_amdgcn_s_barrier();
  }
#undef STAGE

  // ---- epilogue: stage C tile in LDS (256x256 u16 = full 128 KiB), coalesced store
  u16* Cs = lds;
  const int cr = (lane >> 4) << 2, cc = lane & 15;
#pragma unroll
  for (int am = 0; am < 8; ++am)
#pragma unroll
    for (int ni = 0; ni < 4; ++ni)
#pragma unroll
      for (int r = 0; r < 4; ++r)
        Cs[(wm * 128 + (am >> 2) * 64 + (am & 3) * 16 + cr + r) * 256 + wn * 64 + ni * 16 + cc] =
            f2b(acc[am][ni][r]);
  __syncthreads();
#pragma unroll
  for (int pass = 0; pass < 16; ++pass) {
    int row = pass * 16 + (tid >> 5);
    int colb = (tid & 31) << 4;
    *(uint4*)((char*)(C + (size_t)(m0 + row) * N + n0) + colb) =
        *(const uint4*)((const char*)(Cs + row * 256) + colb);
  }
}

// ---------------------------------------------------------------- m97-style BT GEMM
// (r0-r4 proven; used for vT and output GEMMs — 512 blocks = full GPU)
template <int OUT_BF16>
__global__ __launch_bounds__(256) void gemm_bt(const u16* __restrict__ A,
                                               const u16* __restrict__ B,
                                               void* __restrict__ Cv,
                                               int M, int N, int K, int SWZ, int LNT) {
  __shared__ u16 smem[16384];  // As[128*64] | Bs[128*64]; reused as C tile
  u16* As = smem;
  u16* Bs = smem + 8192;
  const int tid = threadIdx.x;
  int g = blockIdx.y * gridDim.x + blockIdx.x;
  int xcd = g & 7, local = g >> 3;
  int mt, nt;
  if (SWZ == 0) {
    mt = xcd * ((int)gridDim.y >> 3) + (local >> LNT);
    nt = local & ((1 << LNT) - 1);
  } else {
    nt = xcd * ((int)gridDim.x >> 3) + (local >> 3);
    mt = local & 7;
  }
  const int m0 = mt * 128, n0 = nt * 128;
  const int wave = tid >> 6, lane = tid & 63;
  const int wm = (wave >> 1) << 6, wn = (wave & 1) << 6;
  f32x4 acc[4][4] = {};
  const int srow = tid >> 3;         // 0..31
  const int scol = (tid & 7) << 3;   // 0..56
  const u16* Ab = A + (size_t)(m0 + srow) * K + scol;
  const u16* Bb = B + (size_t)(n0 + srow) * K + scol;
  u16* Asp = As + srow * 64 + scol;
  u16* Bsp = Bs + srow * 64 + scol;
  const int fm = lane & 15;
  const int fk = (lane >> 4) << 3;
  for (int kt = 0; kt < K; kt += 64) {
#pragma unroll
    for (int i = 0; i < 4; ++i) {
      __builtin_amdgcn_global_load_lds(
          (__attribute__((address_space(1))) unsigned int*)(Ab + (size_t)i * 32 * K + kt),
          (__attribute__((address_space(3))) unsigned int*)(Asp + i * 32 * 64), 16, 0, 0);
      __builtin_amdgcn_global_load_lds(
          (__attribute__((address_space(1))) unsigned int*)(Bb + (size_t)i * 32 * K + kt),
          (__attribute__((address_space(3))) unsigned int*)(Bsp + i * 32 * 64), 16, 0, 0);
    }
    __syncthreads();
#pragma unroll
    for (int kb = 0; kb < 2; ++kb) {
      bf16x8 af[4], bfr[4];
#pragma unroll
      for (int i = 0; i < 4; ++i)
        af[i] = *(const bf16x8*)(As + (wm + i * 16 + fm) * 64 + kb * 32 + fk);
#pragma unroll
      for (int j = 0; j < 4; ++j)
        bfr[j] = *(const bf16x8*)(Bs + (wn + j * 16 + fm) * 64 + kb * 32 + fk);
#pragma unroll
      for (int i = 0; i < 4; ++i)
#pragma unroll
        for (int j = 0; j < 4; ++j)
          acc[i][j] = __builtin_amdgcn_mfma_f32_16x16x32_bf16(af[i], bfr[j], acc[i][j], 0, 0, 0);
    }
    __syncthreads();
  }
  const int cr = (lane >> 4) << 2;
  const int cc = lane & 15;
  if (OUT_BF16) {
    u16* Cs = smem;  // 128x128 u16 = 32 KiB
#pragma unroll
    for (int i = 0; i < 4; ++i)
#pragma unroll
      for (int j = 0; j < 4; ++j)
#pragma unroll
        for (int r = 0; r < 4; ++r)
          Cs[(wm + i * 16 + cr + r) * 128 + wn + j * 16 + cc] = f2b(acc[i][j][r]);
    __syncthreads();
    u16* Cg = (u16*)Cv;
#pragma unroll
    for (int i = 0; i < 8; ++i) {
      int row = (i >> 1) * 32 + (tid >> 3);
      int col = ((i & 1) * 8 + (tid & 7)) * 8;
      *(uint4*)(Cg + (size_t)(m0 + row) * N + n0 + col) = *(const uint4*)(Cs + row * 128 + col);
    }
  } else {
    float* Csf = (float*)smem;  // 64x128 f32 = 32 KiB (two half-passes)
    float* Cg = (float*)Cv;
#pragma unroll
    for (int hh = 0; hh < 2; ++hh) {
      __syncthreads();
      if ((wm >> 6) == hh) {
#pragma unroll
        for (int i = 0; i < 4; ++i)
#pragma unroll
          for (int j = 0; j < 4; ++j)
#pragma unroll
            for (int r = 0; r < 4; ++r)
              Csf[(i * 16 + cr + r) * 128 + wn + j * 16 + cc] = acc[i][j][r];
      }
      __syncthreads();
#pragma unroll
      for (int i = 0; i < 8; ++i) {
        int row = (i >> 1) * 16 + (tid >> 4);
        int col = ((i & 1) * 16 + (tid & 15)) * 4;
        *(float4*)(Cg + (size_t)(m0 + hh * 64 + row) * N + n0 + col) =
            *(const float4*)(Csf + row * 128 + col);
      }
    }
  }
}

// ---------------------------------------------------------------- hedgehog softmax
__global__ __launch_bounds__(256) void hedgehog_sm(const u16* __restrict__ y,
                                                   const float* __restrict__ bias,
                                                   u16* __restrict__ phi, float scale,
                                                   int colbase) {
  int wave = threadIdx.x >> 6, lane = threadIdx.x & 63;
  int rh = blockIdx.x * 4 + wave;
  const u16* yr = y + (size_t)(rh >> 3) * 2048 + colbase + (rh & 7) * 128;
  float a1 = 2.f * (b2f(yr[lane]) + bias[lane]);
  float a2 = 2.f * (b2f(yr[lane + 64]) + bias[lane + 64]);
  float mx = fmaxf(fabsf(a1), fabsf(a2));
#pragma unroll
  for (int off = 32; off; off >>= 1) mx = fmaxf(mx, __shfl_xor(mx, off, 64));
  float e1 = __expf(a1 - mx), e2 = __expf(a2 - mx);
  float n1 = __expf(-a1 - mx), n2 = __expf(-a2 - mx);
  float s = e1 + e2 + n1 + n2;
#pragma unroll
  for (int off = 32; off; off >>= 1) s += __shfl_xor(s, off, 64);
  float inv = scale / s;
  u16* pr = phi + (size_t)rh * 256;
  pr[lane] = f2b(e1 * inv);
  pr[lane + 64] = f2b(e2 * inv);
  pr[lane + 128] = f2b(n1 * inv);
  pr[lane + 192] = f2b(n2 * inv);
}

// ---------------------------------------------------------------- attention: per-chunk KV, C=64
// block g: chunk n = g&127, head h = g>>7. KV[vc][d] = sum_t' vT[vc][t'] k[t'][d].
__global__ __launch_bounds__(256, 1) void attn_kv64(const u16* __restrict__ phi_k,
                                                    const u16* __restrict__ vt,
                                                    u16* __restrict__ kv) {
  __shared__ u16 Kt[18432];  // [256][72]
  int g = blockIdx.x;
  int n = g & 127, h = g >> 7;
  int t0 = n * 64;
  const u16* kg = phi_k + ((size_t)t0 * 8 + h) * 256;  // row stride 2048
  const u16* vg = vt + (size_t)(h * 128) * 8192 + t0;  // vc rows, stride 8192
  int tid = threadIdx.x, lane = tid & 63, w = tid >> 6;
  const int fr = lane & 31, fg = (lane >> 5) << 3;
  const int rbase = (lane >> 5) << 2;

  // ---- Kt[d 0..255][t' 0..63] from global k (stride 72)
  {
    int r4 = (tid & 15) << 2;
    int d0 = (tid >> 4) << 4;
    u16 tmp[4][16];
#pragma unroll
    for (int r = 0; r < 4; ++r) {
      const u16* src = kg + (size_t)(r4 + r) * 2048 + d0;
      *(uint4*)(tmp[r]) = *(const uint4*)src;
      *(uint4*)(tmp[r] + 8) = *(const uint4*)(src + 8);
    }
#pragma unroll
    for (int jj = 0; jj < 16; ++jj) {
      ushort4 pk = make_ushort4(tmp[0][jj], tmp[1][jj], tmp[2][jj], tmp[3][jj]);
      *(ushort4*)(Kt + (d0 + jj) * 72 + r4) = pk;
    }
  }
  __syncthreads();
  const int nd = w << 6;  // wave owns d in [nd, nd+64)
  f32x16 accKV[4][2] = {};
#pragma unroll
  for (int ks = 0; ks < 4; ++ks) {
    bf16x8 a[4], b[2];
#pragma unroll
    for (int mi = 0; mi < 4; ++mi)
      a[mi] = *(const bf16x8*)(vg + (size_t)(mi * 32 + fr) * 8192 + ks * 16 + fg);
#pragma unroll
    for (int nj = 0; nj < 2; ++nj)
      b[nj] = *(const bf16x8*)(Kt + (nd + nj * 32 + fr) * 72 + ks * 16 + fg);
#pragma unroll
    for (int mi = 0; mi < 4; ++mi)
#pragma unroll
      for (int nj = 0; nj < 2; ++nj)
        accKV[mi][nj] =
            __builtin_amdgcn_mfma_f32_32x32x16_bf16(a[mi], b[nj], accKV[mi][nj], 0, 0, 0);
  }
  {
    u16* kvg = kv + (size_t)g * 32768;
#pragma unroll
    for (int mi = 0; mi < 4; ++mi)
#pragma unroll
      for (int nj = 0; nj < 2; ++nj) {
        f32x16 acc = accKV[mi][nj];
        int d = nd + nj * 32 + (lane & 31);
#pragma unroll
        for (int r = 0; r < 16; ++r) {
          int vc = mi * 32 + (r & 3) + ((r >> 2) << 3) + rbase;
          kvg[(size_t)vc * 256 + d] = f2b(acc[r]);
        }
      }
  }
}

// ---------------------------------------------------------------- attention phase B, C=64
// in-place exclusive prefix over 128 chunk-KVs per h; 4 bf16/thread, fp32 carry.
__global__ __launch_bounds__(256) void kv_scan64(u16* __restrict__ kv) {
  int idx = blockIdx.x * 256 + threadIdx.x;  // 0..65535
  int h = idx >> 13;                         // 8192 lanes per h
  int e4 = idx & 8191;
  u16* p = kv + (size_t)h * 4194304 + (size_t)e4 * 4;
  float run[4] = {};
#pragma unroll 4
  for (int nn = 0; nn < 128; ++nn) {
    uint2 raw = *(const uint2*)p;
    u16* rv = (u16*)&raw;
    uint2 outw;
    u16* ov = (u16*)&outw;
#pragma unroll
    for (int i = 0; i < 4; ++i) {
      float v = b2f(rv[i]);
      ov[i] = f2b(run[i]);
      run[i] += v;
    }
    *(uint2*)p = outw;
    p += 32768;
  }
}

// ---------------------------------------------------------------- attention fused o, C=64
// block g: chunk n = g&127, head h = g>>7. q frags preloaded once (shared A-operand);
// merged loop: scores MFMA chain + q@S MFMA chains (independent), 3 loads/iter;
// then mask -> At LDS -> o += At@vT; single fp32 o write (no RMW).
__global__ __launch_bounds__(256, 1) void attn_fused64(const u16* __restrict__ phi_q,
                                                       const u16* __restrict__ phi_k,
                                                       const u16* __restrict__ vt,
                                                       const u16* __restrict__ kv,
                                                       float* __restrict__ o) {
  __shared__ u16 At[8704];  // [64][136]
  int g = blockIdx.x;
  int n = g & 127, h = g >> 7;
  int t0 = n * 64;
  const u16* qg = phi_q + ((size_t)t0 * 8 + h) * 256;  // row stride 2048
  const u16* kg = phi_k + ((size_t)t0 * 8 + h) * 256;
  const u16* vg = vt + (size_t)(h * 128) * 8192 + t0;  // vc rows, stride 8192
  const u16* sg = kv + (size_t)g * 32768;              // S[vc][d], stride 256
  int tid = threadIdx.x, lane = tid & 63, w = tid >> 6;
  const int fr = lane & 31, fg = (lane >> 5) << 3;
  const int rbase = (lane >> 5) << 2;
  const int mw = (w >> 1) << 5;  // t tile (0/32)
  const int nw = (w & 1) << 5;   // t' tile (0/32)
  const int nv = (w & 1) << 6;   // vc half (0/64)

  // ---- preload q fragments (row mw+fr) — A-operand of BOTH scores and q@S
  bf16x8 qf[16];
  {
    const u16* qrow = qg + (size_t)(mw + fr) * 2048 + fg;
#pragma unroll
    for (int ks = 0; ks < 16; ++ks) qf[ks] = *(const bf16x8*)(qrow + ks * 16);
  }

  // ---- merged loop: scores (accS) + q@S (accO[0/1]) — 3 independent MFMA chains
  f32x16 accS = {};
  f32x16 accO[2] = {};
  {
    const u16* krow = kg + (size_t)(nw + fr) * 2048 + fg;
    const u16* srow0 = sg + (size_t)(nv + fr) * 256 + fg;
    const u16* srow1 = sg + (size_t)(nv + 32 + fr) * 256 + fg;
#pragma unroll
    for (int ks = 0; ks < 16; ++ks) {
      bf16x8 kb = *(const bf16x8*)(krow + ks * 16);
      bf16x8 sb0 = *(const bf16x8*)(srow0 + ks * 16);
      bf16x8 sb1 = *(const bf16x8*)(srow1 + ks * 16);
      accS = __builtin_amdgcn_mfma_f32_32x32x16_bf16(qf[ks], kb, accS, 0, 0, 0);
      accO[0] = __builtin_amdgcn_mfma_f32_32x32x16_bf16(qf[ks], sb0, accO[0], 0, 0, 0);
      accO[1] = __builtin_amdgcn_mfma_f32_32x32x16_bf16(qf[ks], sb1, accO[1], 0, 0, 0);
    }
  }
  // ---- mask + At (causal incl diagonal)
  {
    int col = nw + (lane & 31);
#pragma unroll
    for (int r = 0; r < 16; ++r) {
      int row = mw + (r & 3) + ((r >> 2) << 3) + rbase;
      At[row * 136 + col] = f2b(col <= row ? accS[r] : 0.f);
    }
  }
  __syncthreads();
  // ---- o += At @ vT : wave -> rows [mw,mw+32) x vc [nv,nv+64)
#pragma unroll
  for (int ks = 0; ks < 4; ++ks) {
    bf16x8 a = *(const bf16x8*)(At + (mw + fr) * 136 + ks * 16 + fg);
#pragma unroll
    for (int nj = 0; nj < 2; ++nj) {
      bf16x8 b = *(const bf16x8*)(vg + (size_t)(nv + nj * 32 + fr) * 8192 + ks * 16 + fg);
      accO[nj] = __builtin_amdgcn_mfma_f32_32x32x16_bf16(a, b, accO[nj], 0, 0, 0);
    }
  }
  {
    float* og = o + ((size_t)t0 * 8 + h) * 128;  // row stride 1024
#pragma unroll
    for (int nj = 0; nj < 2; ++nj) {
      int vc = nv + nj * 32 + (lane & 31);
#pragma unroll
      for (int r = 0; r < 16; ++r) {
        int row = mw + (r & 3) + ((r >> 2) << 3) + rbase;
        og[(size_t)row * 1024 + vc] = accO[nj][r];
      }
    }
  }
}

// ---------------------------------------------------------------- rmsnorm (per 1024-dim row)
__global__ __launch_bounds__(256) void rmsnorm_k(const float* __restrict__ o,
                                                 u16* __restrict__ on) {
  __shared__ float red[4];
  int row = blockIdx.x;
  const float* orow = o + (size_t)row * 1024;
  int tid = threadIdx.x;
  float4 v = ((const float4*)orow)[tid];
  float ss = v.x * v.x + v.y * v.y + v.z * v.z + v.w * v.w;
#pragma unroll
  for (int off = 32; off; off >>= 1) ss += __shfl_xor(ss, off, 64);
  if ((tid & 63) == 0) red[tid >> 6] = ss;
  __syncthreads();
  float tot = red[0] + red[1] + red[2] + red[3];
  float rms = rsqrtf(tot * (1.f / 1024.f) + 1e-5f);
  ushort4 r = make_ushort4(f2b(v.x * rms), f2b(v.y * rms), f2b(v.z * rms), f2b(v.w * rms));
  ((ushort4*)(on + (size_t)row * 1024))[tid] = r;
}

// ---------------------------------------------------------------- launch
extern "C" void kernel_launch(void* const* d_in, const int* in_sizes, int n_in,
                              void* d_out, int out_size, void* d_ws, size_t ws_size,
                              hipStream_t stream) {
  const float* x     = (const float*)d_in[0];
  const float* Wq    = (const float*)d_in[1];
  const float* Wk    = (const float*)d_in[2];
  const float* Wv    = (const float*)d_in[3];
  const float* Wo    = (const float*)d_in[4];
  const float* fmq_w = (const float*)d_in[5];
  const float* fmq_b = (const float*)d_in[6];
  const float* fmk_w = (const float*)d_in[7];
  const float* fmk_b = (const float*)d_in[8];

  // Workspace 184 MiB. kvb 64 MiB [0,64MiB) aliases xb[0,16), yb[16,48), onb[48,64).
  // Temporal safety (stream-ordered, per batch): xb dead after vT GEMM (precedes
  // attn_kv64's kv write); yb dead after hedgehog; onb only live rmsnorm->out-GEMM,
  // during which kv is dead (attn_fused64 consumed it); next batch's kv write comes
  // after this batch's out-GEMM.
  char* ws = (char*)d_ws;
  u16*   kvb  = (u16*)(ws + 0);            // 64 MiB (128 chunks x 8 h x 64 KiB)
  u16*   xb   = (u16*)(ws + 0);            // 16 MiB
  u16*   yb   = (u16*)(ws + 16777216);     // 32 MiB (merged q|k, [8192][2048])
  u16*   onb  = (u16*)(ws + 50331648);     // 16 MiB
  u16*   phiq = (u16*)(ws + 67108864);     // 32 MiB
  u16*   phik = (u16*)(ws + 100663296);    // 32 MiB
  u16*   vtb  = (u16*)(ws + 134217728);    // 16 MiB ([1024 vc-rows][8192 t])
  float* obuf = (float*)(ws + 150994944);  // 32 MiB
  u16*   wqkc = (u16*)(ws + 184549376);    // 4 MiB ([2048][1024]: q rows | k rows)
  u16*   wvb  = (u16*)(ws + 188743680);    // 2 MiB
  u16*   wob  = (u16*)(ws + 190840832);    // 2 MiB -> end 192937984 (184 MiB)

  // weight prep (once)
  cast_bf16<<<1024, 256, 0, stream>>>(Wv, wvb, 262144);
  cast_bf16<<<1024, 256, 0, stream>>>(Wo, wob, 262144);
  fold_w<<<1024, 256, 0, stream>>>(Wq, fmq_w, wqkc);
  fold_w<<<1024, 256, 0, stream>>>(Wk, fmk_w, wqkc + 1048576);

  for (int b = 0; b < 2; ++b) {
    const float* xsrc = x + (size_t)b * 8388608;
    float* osrc = (float*)d_out + (size_t)b * 8388608;
    cast_bf16<<<8192, 256, 0, stream>>>(xsrc, xb, 2097152);
    // merged q|k projection: [8192][2048] — 256² 8-phase kernel (32x8 tiles, 256 blocks)
    gemm256<<<256, 512, 0, stream>>>(xb, wqkc, yb, 8192, 2048, 1024, 3);
    hedgehog_sm<<<16384, 256, 0, stream>>>(yb, fmq_b, phiq, 0.0625f, 0);     // 256^-0.5
    hedgehog_sm<<<16384, 256, 0, stream>>>(yb, fmk_b, phik, 1.0f, 1024);
    // v^T via operand swap: C[1024][8192] = Wv @ x^T — gemm_bt, 512 blocks
    gemm_bt<1><<<dim3(64, 8), 256, 0, stream>>>(wvb, xb, vtb, 1024, 8192, 1024, 1, 0);
    // attention, C=64: KV -> exclusive scan -> fused (intra + inter) o
    attn_kv64<<<1024, 256, 0, stream>>>(phik, vtb, kvb);
    kv_scan64<<<256, 256, 0, stream>>>(kvb);
    attn_fused64<<<1024, 256, 0, stream>>>(phiq, phik, vtb, kvb, obuf);
    // rmsnorm + output projection (fp32 out) — gemm_bt, 512 blocks
    rmsnorm_k<<<8192, 256, 0, stream>>>(obuf, onb);
    gemm_bt<0><<<dim3(8, 64), 256, 0, stream>>>(onb, wob, osrc, 8192, 1024, 1024, 0, 3);
  }
}

// Round 7
// 642.631 us; speedup vs baseline: 1.0932x; 1.0011x over previous
//
#include <hip/hip_runtime.h>
#include <stdint.h>

typedef unsigned short u16;
typedef __bf16 bf16x8 __attribute__((ext_vector_type(8)));
typedef float f32x4 __attribute__((ext_vector_type(4)));
typedef float f32x16 __attribute__((ext_vector_type(16)));

__device__ __forceinline__ u16 f2b(float f) {
  union { float f; unsigned u; } v; v.f = f;
  unsigned r = v.u + 0x7fffu + ((v.u >> 16) & 1u);
  return (u16)(r >> 16);
}
__device__ __forceinline__ float b2f(u16 b) {
  union { unsigned u; float f; } v; v.u = ((unsigned)b) << 16;
  return v.f;
}

// st-swizzle for 64B-row LDS slots: flips 16B-chunk bits 4-5 with row bits.
__device__ __forceinline__ int swz64(int b) {
  return b ^ (((((b >> 6) & 3) ^ ((b >> 8) & 1))) << 4);
}

#define SB0() __builtin_amdgcn_sched_barrier(0)

// ---------------------------------------------------------------- cast fp32 -> bf16
__global__ __launch_bounds__(256) void cast_bf16(const float* __restrict__ in,
                                                 u16* __restrict__ out, int n4) {
  int i = blockIdx.x * 256 + threadIdx.x;
  if (i >= n4) return;
  float4 f = ((const float4*)in)[i];
  ushort4 r = make_ushort4(f2b(f.x), f2b(f.y), f2b(f.z), f2b(f.w));
  ((ushort4*)out)[i] = r;
}

// ---------------------------------------------------------------- fold fm weight into projection
// out[h*128+j, i] = sum_d fmw[j,d] * W[h*128+d, i]   (bf16 out)
__global__ __launch_bounds__(256) void fold_w(const float* __restrict__ W,
                                              const float* __restrict__ fmw,
                                              u16* __restrict__ out) {
  int hj = blockIdx.x;
  int h = hj >> 7, j = hj & 127;
  int i0 = threadIdx.x * 4;
  float a0 = 0.f, a1 = 0.f, a2 = 0.f, a3 = 0.f;
  const float* Wh = W + (size_t)(h * 128) * 1024 + i0;
  const float* fw = fmw + j * 128;
  for (int d = 0; d < 128; ++d) {
    float wv = fw[d];
    const float* wr = Wh + (size_t)d * 1024;
    a0 += wv * wr[0]; a1 += wv * wr[1]; a2 += wv * wr[2]; a3 += wv * wr[3];
  }
  ushort4 r = make_ushort4(f2b(a0), f2b(a1), f2b(a2), f2b(a3));
  ((ushort4*)(out + (size_t)hj * 1024))[threadIdx.x] = r;
}

// ---------------------------------------------------------------- 256x256 8-phase BT GEMM
// C[M,N] = A[M,K] @ B[N,K]^T, all bf16. 512 threads = 8 waves (2M x 4N).
// LDS 128 KiB double-buffered, counted vmcnt. Used for the q|k GEMM (256 blocks).
__global__ __launch_bounds__(512, 2) void gemm256(const u16* __restrict__ A,
                                                  const u16* __restrict__ B,
                                                  u16* __restrict__ C,
                                                  int M, int N, int K, int LNT) {
  __shared__ u16 lds[65536];  // 128 KiB
  const int tid = threadIdx.x, w = tid >> 6, lane = tid & 63;
  int g = blockIdx.x;
  int wg = (g & 7) * ((int)gridDim.x >> 3) + (g >> 3);  // XCD swizzle (nwg%8==0)
  const int nt = wg & ((1 << LNT) - 1), mt = wg >> LNT;
  const int m0 = mt << 8, n0 = nt << 8;
  const int wm = w >> 2, wn = w & 3;
  const int fm = lane & 15, fkb = (lane >> 4) << 4;  // frag row, k byte offset

  int so0 = w * 1024 + lane * 16;
  int so1 = so0 + 8192;
  const int p0s = swz64(so0), p1s = swz64(so1);
  const size_t ga0 = (size_t)(p0s >> 6) * K + ((p0s & 63) >> 1);
  const size_t ga1 = (size_t)(p1s >> 6) * K + ((p1s & 63) >> 1);
  so0 >>= 1; so1 >>= 1;  // u16 offsets
#define STAGE(g0, slot)                                                               \
  do {                                                                                \
    __builtin_amdgcn_global_load_lds(                                                 \
        (const __attribute__((address_space(1))) unsigned int*)((g0) + ga0),          \
        (__attribute__((address_space(3))) unsigned int*)((slot) + so0), 16, 0, 0);   \
    __builtin_amdgcn_global_load_lds(                                                 \
        (const __attribute__((address_space(1))) unsigned int*)((g0) + ga1),          \
        (__attribute__((address_space(3))) unsigned int*)((slot) + so1), 16, 0, 0);   \
  } while (0)

  int aoff[2][4], boff[4];
#pragma unroll
  for (int mh = 0; mh < 2; ++mh)
#pragma unroll
    for (int mi = 0; mi < 4; ++mi)
      aoff[mh][mi] = swz64((wm * 128 + mh * 64 + mi * 16 + fm) * 64 + fkb) >> 1;
#pragma unroll
  for (int ni = 0; ni < 4; ++ni)
    boff[ni] = swz64((wn * 64 + ni * 16 + fm) * 64 + fkb) >> 1;

  const u16* Ag = A + (size_t)m0 * K;
  const u16* Bg = B + (size_t)n0 * K;
  const int NT = K >> 6;
  f32x4 acc[8][4] = {};

  STAGE(Ag, lds);
  STAGE(Bg, lds + 32768);
  STAGE(Ag + 32, lds + 8192);
  STAGE(Bg + 32, lds + 32768 + 8192);
  STAGE(Ag + 64, lds + 16384);
  STAGE(Bg + 64, lds + 32768 + 16384);
  asm volatile("s_waitcnt vmcnt(4)" ::: "memory");
  __builtin_amdgcn_s_barrier();

  for (int t = 0; t < NT; ++t) {
    const int buf = t & 1, nb = buf ^ 1;
    const u16* As0 = lds + buf * 16384;
    const u16* As1 = As0 + 8192;
    const u16* Bs0 = lds + 32768 + buf * 16384;
    const u16* Bs1 = Bs0 + 8192;
    bf16x8 a[4], bfr[4];

    // ---- phase 0: (mh0, kk0)
#pragma unroll
    for (int mi = 0; mi < 4; ++mi) a[mi] = *(const bf16x8*)(As0 + aoff[0][mi]);
#pragma unroll
    for (int ni = 0; ni < 4; ++ni) bfr[ni] = *(const bf16x8*)(Bs0 + boff[ni]);
    if (t + 1 < NT) STAGE(Ag + (t + 1) * 64 + 32, lds + nb * 16384 + 8192);
    __builtin_amdgcn_s_barrier();
    asm volatile("s_waitcnt lgkmcnt(0)" ::: "memory");
    SB0();
    __builtin_amdgcn_s_setprio(1);
#pragma unroll
    for (int mi = 0; mi < 4; ++mi)
#pragma unroll
      for (int ni = 0; ni < 4; ++ni)
        acc[mi][ni] = __builtin_amdgcn_mfma_f32_16x16x32_bf16(a[mi], bfr[ni], acc[mi][ni], 0, 0, 0);
    __builtin_amdgcn_s_setprio(0);
    __builtin_amdgcn_s_barrier();

    // ---- phase 1: (mh1, kk0)
#pragma unroll
    for (int mi = 0; mi < 4; ++mi) a[mi] = *(const bf16x8*)(As0 + aoff[1][mi]);
    if (t + 1 < NT) STAGE(Bg + (t + 1) * 64 + 32, lds + 32768 + nb * 16384 + 8192);
    __builtin_amdgcn_s_barrier();
    asm volatile("s_waitcnt lgkmcnt(0)" ::: "memory");
    SB0();
    __builtin_amdgcn_s_setprio(1);
#pragma unroll
    for (int mi = 0; mi < 4; ++mi)
#pragma unroll
      for (int ni = 0; ni < 4; ++ni)
        acc[4 + mi][ni] =
            __builtin_amdgcn_mfma_f32_16x16x32_bf16(a[mi], bfr[ni], acc[4 + mi][ni], 0, 0, 0);
    __builtin_amdgcn_s_setprio(0);
    __builtin_amdgcn_s_barrier();

    // ---- phase 2: (mh0, kk1)
#pragma unroll
    for (int mi = 0; mi < 4; ++mi) a[mi] = *(const bf16x8*)(As1 + aoff[0][mi]);
#pragma unroll
    for (int ni = 0; ni < 4; ++ni) bfr[ni] = *(const bf16x8*)(Bs1 + boff[ni]);
    if (t + 2 < NT) STAGE(Ag + (t + 2) * 64, lds + buf * 16384);
    __builtin_amdgcn_s_barrier();
    asm volatile("s_waitcnt lgkmcnt(0)" ::: "memory");
    SB0();
    __builtin_amdgcn_s_setprio(1);
#pragma unroll
    for (int mi = 0; mi < 4; ++mi)
#pragma unroll
      for (int ni = 0; ni < 4; ++ni)
        acc[mi][ni] = __builtin_amdgcn_mfma_f32_16x16x32_bf16(a[mi], bfr[ni], acc[mi][ni], 0, 0, 0);
    __builtin_amdgcn_s_setprio(0);
    __builtin_amdgcn_s_barrier();

    // ---- phase 3: (mh1, kk1)
#pragma unroll
    for (int mi = 0; mi < 4; ++mi) a[mi] = *(const bf16x8*)(As1 + aoff[1][mi]);
    if (t + 2 < NT) STAGE(Bg + (t + 2) * 64, lds + 32768 + buf * 16384);
    __builtin_amdgcn_s_barrier();
    asm volatile("s_waitcnt lgkmcnt(0)" ::: "memory");
    SB0();
    __builtin_amdgcn_s_setprio(1);
#pragma unroll
    for (int mi = 0; mi < 4; ++mi)
#pragma unroll
      for (int ni = 0; ni < 4; ++ni)
        acc[4 + mi][ni] =
            __builtin_amdgcn_mfma_f32_16x16x32_bf16(a[mi], bfr[ni], acc[4 + mi][ni], 0, 0, 0);
    __builtin_amdgcn_s_setprio(0);
    if (t < NT - 2)
      asm volatile("s_waitcnt vmcnt(4)" ::: "memory");
    else
      asm volatile("s_waitcnt vmcnt(0)" ::: "memory");
    __builtin_amdgcn_s_barrier();
  }
#undef STAGE

  // ---- epilogue: stage C tile in LDS (256x256 u16 = full 128 KiB), coalesced store
  u16* Cs = lds;
  const int cr = (lane >> 4) << 2, cc = lane & 15;
#pragma unroll
  for (int am = 0; am < 8; ++am)
#pragma unroll
    for (int ni = 0; ni < 4; ++ni)
#pragma unroll
      for (int r = 0; r < 4; ++r)
        Cs[(wm * 128 + (am >> 2) * 64 + (am & 3) * 16 + cr + r) * 256 + wn * 64 + ni * 16 + cc] =
            f2b(acc[am][ni][r]);
  __syncthreads();
#pragma unroll
  for (int pass = 0; pass < 16; ++pass) {
    int row = pass * 16 + (tid >> 5);
    int colb = (tid & 31) << 4;
    *(uint4*)((char*)(C + (size_t)(m0 + row) * N + n0) + colb) =
        *(const uint4*)((const char*)(Cs + row * 256) + colb);
  }
}

// ---------------------------------------------------------------- m97-style BT GEMM
// (r0-r4 proven; used for vT and output GEMMs — 512 blocks = full GPU)
template <int OUT_BF16>
__global__ __launch_bounds__(256) void gemm_bt(const u16* __restrict__ A,
                                               const u16* __restrict__ B,
                                               void* __restrict__ Cv,
                                               int M, int N, int K, int SWZ, int LNT) {
  __shared__ u16 smem[16384];  // As[128*64] | Bs[128*64]; reused as C tile
  u16* As = smem;
  u16* Bs = smem + 8192;
  const int tid = threadIdx.x;
  int g = blockIdx.y * gridDim.x + blockIdx.x;
  int xcd = g & 7, local = g >> 3;
  int mt, nt;
  if (SWZ == 0) {
    mt = xcd * ((int)gridDim.y >> 3) + (local >> LNT);
    nt = local & ((1 << LNT) - 1);
  } else {
    nt = xcd * ((int)gridDim.x >> 3) + (local >> 3);
    mt = local & 7;
  }
  const int m0 = mt * 128, n0 = nt * 128;
  const int wave = tid >> 6, lane = tid & 63;
  const int wm = (wave >> 1) << 6, wn = (wave & 1) << 6;
  f32x4 acc[4][4] = {};
  const int srow = tid >> 3;         // 0..31
  const int scol = (tid & 7) << 3;   // 0..56
  const u16* Ab = A + (size_t)(m0 + srow) * K + scol;
  const u16* Bb = B + (size_t)(n0 + srow) * K + scol;
  u16* Asp = As + srow * 64 + scol;
  u16* Bsp = Bs + srow * 64 + scol;
  const int fm = lane & 15;
  const int fk = (lane >> 4) << 3;
  for (int kt = 0; kt < K; kt += 64) {
#pragma unroll
    for (int i = 0; i < 4; ++i) {
      __builtin_amdgcn_global_load_lds(
          (__attribute__((address_space(1))) unsigned int*)(Ab + (size_t)i * 32 * K + kt),
          (__attribute__((address_space(3))) unsigned int*)(Asp + i * 32 * 64), 16, 0, 0);
      __builtin_amdgcn_global_load_lds(
          (__attribute__((address_space(1))) unsigned int*)(Bb + (size_t)i * 32 * K + kt),
          (__attribute__((address_space(3))) unsigned int*)(Bsp + i * 32 * 64), 16, 0, 0);
    }
    __syncthreads();
#pragma unroll
    for (int kb = 0; kb < 2; ++kb) {
      bf16x8 af[4], bfr[4];
#pragma unroll
      for (int i = 0; i < 4; ++i)
        af[i] = *(const bf16x8*)(As + (wm + i * 16 + fm) * 64 + kb * 32 + fk);
#pragma unroll
      for (int j = 0; j < 4; ++j)
        bfr[j] = *(const bf16x8*)(Bs + (wn + j * 16 + fm) * 64 + kb * 32 + fk);
#pragma unroll
      for (int i = 0; i < 4; ++i)
#pragma unroll
        for (int j = 0; j < 4; ++j)
          acc[i][j] = __builtin_amdgcn_mfma_f32_16x16x32_bf16(af[i], bfr[j], acc[i][j], 0, 0, 0);
    }
    __syncthreads();
  }
  const int cr = (lane >> 4) << 2;
  const int cc = lane & 15;
  if (OUT_BF16) {
    u16* Cs = smem;  // 128x128 u16 = 32 KiB
#pragma unroll
    for (int i = 0; i < 4; ++i)
#pragma unroll
      for (int j = 0; j < 4; ++j)
#pragma unroll
        for (int r = 0; r < 4; ++r)
          Cs[(wm + i * 16 + cr + r) * 128 + wn + j * 16 + cc] = f2b(acc[i][j][r]);
    __syncthreads();
    u16* Cg = (u16*)Cv;
#pragma unroll
    for (int i = 0; i < 8; ++i) {
      int row = (i >> 1) * 32 + (tid >> 3);
      int col = ((i & 1) * 8 + (tid & 7)) * 8;
      *(uint4*)(Cg + (size_t)(m0 + row) * N + n0 + col) = *(const uint4*)(Cs + row * 128 + col);
    }
  } else {
    float* Csf = (float*)smem;  // 64x128 f32 = 32 KiB (two half-passes)
    float* Cg = (float*)Cv;
#pragma unroll
    for (int hh = 0; hh < 2; ++hh) {
      __syncthreads();
      if ((wm >> 6) == hh) {
#pragma unroll
        for (int i = 0; i < 4; ++i)
#pragma unroll
          for (int j = 0; j < 4; ++j)
#pragma unroll
            for (int r = 0; r < 4; ++r)
              Csf[(i * 16 + cr + r) * 128 + wn + j * 16 + cc] = acc[i][j][r];
      }
      __syncthreads();
#pragma unroll
      for (int i = 0; i < 8; ++i) {
        int row = (i >> 1) * 16 + (tid >> 4);
        int col = ((i & 1) * 16 + (tid & 15)) * 4;
        *(float4*)(Cg + (size_t)(m0 + hh * 64 + row) * N + n0 + col) =
            *(const float4*)(Csf + row * 128 + col);
      }
    }
  }
}

// ---------------------------------------------------------------- hedgehog softmax
__global__ __launch_bounds__(256) void hedgehog_sm(const u16* __restrict__ y,
                                                   const float* __restrict__ bias,
                                                   u16* __restrict__ phi, float scale,
                                                   int colbase) {
  int wave = threadIdx.x >> 6, lane = threadIdx.x & 63;
  int rh = blockIdx.x * 4 + wave;
  const u16* yr = y + (size_t)(rh >> 3) * 2048 + colbase + (rh & 7) * 128;
  float a1 = 2.f * (b2f(yr[lane]) + bias[lane]);
  float a2 = 2.f * (b2f(yr[lane + 64]) + bias[lane + 64]);
  float mx = fmaxf(fabsf(a1), fabsf(a2));
#pragma unroll
  for (int off = 32; off; off >>= 1) mx = fmaxf(mx, __shfl_xor(mx, off, 64));
  float e1 = __expf(a1 - mx), e2 = __expf(a2 - mx);
  float n1 = __expf(-a1 - mx), n2 = __expf(-a2 - mx);
  float s = e1 + e2 + n1 + n2;
#pragma unroll
  for (int off = 32; off; off >>= 1) s += __shfl_xor(s, off, 64);
  float inv = scale / s;
  u16* pr = phi + (size_t)rh * 256;
  pr[lane] = f2b(e1 * inv);
  pr[lane + 64] = f2b(e2 * inv);
  pr[lane + 128] = f2b(n1 * inv);
  pr[lane + 192] = f2b(n2 * inv);
}

// ---------------------------------------------------------------- attention: per-chunk KV, C=64
// block g: chunk n = g&127, head h = g>>7. KV[vc][d] = sum_t' vT[vc][t'] k[t'][d].
__global__ __launch_bounds__(256, 1) void attn_kv64(const u16* __restrict__ phi_k,
                                                    const u16* __restrict__ vt,
                                                    u16* __restrict__ kv) {
  __shared__ u16 Kt[18432];  // [256][72]
  int g = blockIdx.x;
  int n = g & 127, h = g >> 7;
  int t0 = n * 64;
  const u16* kg = phi_k + ((size_t)t0 * 8 + h) * 256;  // row stride 2048
  const u16* vg = vt + (size_t)(h * 128) * 8192 + t0;  // vc rows, stride 8192
  int tid = threadIdx.x, lane = tid & 63, w = tid >> 6;
  const int fr = lane & 31, fg = (lane >> 5) << 3;
  const int rbase = (lane >> 5) << 2;

  // ---- Kt[d 0..255][t' 0..63] from global k (stride 72)
  {
    int r4 = (tid & 15) << 2;
    int d0 = (tid >> 4) << 4;
    u16 tmp[4][16];
#pragma unroll
    for (int r = 0; r < 4; ++r) {
      const u16* src = kg + (size_t)(r4 + r) * 2048 + d0;
      *(uint4*)(tmp[r]) = *(const uint4*)src;
      *(uint4*)(tmp[r] + 8) = *(const uint4*)(src + 8);
    }
#pragma unroll
    for (int jj = 0; jj < 16; ++jj) {
      ushort4 pk = make_ushort4(tmp[0][jj], tmp[1][jj], tmp[2][jj], tmp[3][jj]);
      *(ushort4*)(Kt + (d0 + jj) * 72 + r4) = pk;
    }
  }
  __syncthreads();
  const int nd = w << 6;  // wave owns d in [nd, nd+64)
  f32x16 accKV[4][2] = {};
#pragma unroll
  for (int ks = 0; ks < 4; ++ks) {
    bf16x8 a[4], b[2];
#pragma unroll
    for (int mi = 0; mi < 4; ++mi)
      a[mi] = *(const bf16x8*)(vg + (size_t)(mi * 32 + fr) * 8192 + ks * 16 + fg);
#pragma unroll
    for (int nj = 0; nj < 2; ++nj)
      b[nj] = *(const bf16x8*)(Kt + (nd + nj * 32 + fr) * 72 + ks * 16 + fg);
#pragma unroll
    for (int mi = 0; mi < 4; ++mi)
#pragma unroll
      for (int nj = 0; nj < 2; ++nj)
        accKV[mi][nj] =
            __builtin_amdgcn_mfma_f32_32x32x16_bf16(a[mi], b[nj], accKV[mi][nj], 0, 0, 0);
  }
  {
    u16* kvg = kv + (size_t)g * 32768;
#pragma unroll
    for (int mi = 0; mi < 4; ++mi)
#pragma unroll
      for (int nj = 0; nj < 2; ++nj) {
        f32x16 acc = accKV[mi][nj];
        int d = nd + nj * 32 + (lane & 31);
#pragma unroll
        for (int r = 0; r < 16; ++r) {
          int vc = mi * 32 + (r & 3) + ((r >> 2) << 3) + rbase;
          kvg[(size_t)vc * 256 + d] = f2b(acc[r]);
        }
      }
  }
}

// ---------------------------------------------------------------- attention phase B, C=64
// in-place exclusive prefix over 128 chunk-KVs per h; 4 bf16/thread, fp32 carry.
__global__ __launch_bounds__(256) void kv_scan64(u16* __restrict__ kv) {
  int idx = blockIdx.x * 256 + threadIdx.x;  // 0..65535
  int h = idx >> 13;                         // 8192 lanes per h
  int e4 = idx & 8191;
  u16* p = kv + (size_t)h * 4194304 + (size_t)e4 * 4;
  float run[4] = {};
#pragma unroll 4
  for (int nn = 0; nn < 128; ++nn) {
    uint2 raw = *(const uint2*)p;
    u16* rv = (u16*)&raw;
    uint2 outw;
    u16* ov = (u16*)&outw;
#pragma unroll
    for (int i = 0; i < 4; ++i) {
      float v = b2f(rv[i]);
      ov[i] = f2b(run[i]);
      run[i] += v;
    }
    *(uint2*)p = outw;
    p += 32768;
  }
}

// ---------------------------------------------------------------- attention fused o, C=64
// block g: chunk n = g&127, head h = g>>7. Merged scores + q@S with explicit
// register double-buffered load batches (A/B sets, 16 loads each) — WAR structure
// forces ~128 operand VGPRs live so 16-32 loads stay in flight per wave.
// Then mask -> At LDS -> o += At@vT; single fp32 o write (no RMW).
__global__ __launch_bounds__(256, 1) void attn_fused64(const u16* __restrict__ phi_q,
                                                       const u16* __restrict__ phi_k,
                                                       const u16* __restrict__ vt,
                                                       const u16* __restrict__ kv,
                                                       float* __restrict__ o) {
  __shared__ u16 At[8704];  // [64][136]
  int g = blockIdx.x;
  int n = g & 127, h = g >> 7;
  int t0 = n * 64;
  const u16* qg = phi_q + ((size_t)t0 * 8 + h) * 256;  // row stride 2048
  const u16* kg = phi_k + ((size_t)t0 * 8 + h) * 256;
  const u16* vg = vt + (size_t)(h * 128) * 8192 + t0;  // vc rows, stride 8192
  const u16* sg = kv + (size_t)g * 32768;              // S[vc][d], stride 256
  int tid = threadIdx.x, lane = tid & 63, w = tid >> 6;
  const int fr = lane & 31, fg = (lane >> 5) << 3;
  const int rbase = (lane >> 5) << 2;
  const int mw = (w >> 1) << 5;  // t tile (0/32)
  const int nw = (w & 1) << 5;   // t' tile (0/32)
  const int nv = (w & 1) << 6;   // vc half (0/64)

  const u16* qrow = qg + (size_t)(mw + fr) * 2048 + fg;
  const u16* krow = kg + (size_t)(nw + fr) * 2048 + fg;
  const u16* srow0 = sg + (size_t)(nv + fr) * 256 + fg;
  const u16* srow1 = sg + (size_t)(nv + 32 + fr) * 256 + fg;

  f32x16 accS = {};
  f32x16 accO0 = {};
  f32x16 accO1 = {};
  bf16x8 qA[4], kA[4], s0A[4], s1A[4];
  bf16x8 qB[4], kB[4], s0B[4], s1B[4];

#define LOADB(Q, Kk, S0, S1, base)                          \
  {                                                         \
    _Pragma("unroll") for (int j = 0; j < 4; ++j) {         \
      Q[j] = *(const bf16x8*)(qrow + ((base) + j) * 16);    \
      Kk[j] = *(const bf16x8*)(krow + ((base) + j) * 16);   \
      S0[j] = *(const bf16x8*)(srow0 + ((base) + j) * 16);  \
      S1[j] = *(const bf16x8*)(srow1 + ((base) + j) * 16);  \
    }                                                       \
  }
#define COMPB(Q, Kk, S0, S1)                                                          \
  {                                                                                   \
    _Pragma("unroll") for (int j = 0; j < 4; ++j) {                                   \
      accS = __builtin_amdgcn_mfma_f32_32x32x16_bf16(Q[j], Kk[j], accS, 0, 0, 0);     \
      accO0 = __builtin_amdgcn_mfma_f32_32x32x16_bf16(Q[j], S0[j], accO0, 0, 0, 0);   \
      accO1 = __builtin_amdgcn_mfma_f32_32x32x16_bf16(Q[j], S1[j], accO1, 0, 0, 0);   \
    }                                                                                 \
  }

  LOADB(qA, kA, s0A, s1A, 0)    // 16 loads in flight
  LOADB(qB, kB, s0B, s1B, 4)    // 32 in flight
  COMPB(qA, kA, s0A, s1A)       // waits on A only; B still in flight
  LOADB(qA, kA, s0A, s1A, 8)    // refill A while B lands
  COMPB(qB, kB, s0B, s1B)
  LOADB(qB, kB, s0B, s1B, 12)
  COMPB(qA, kA, s0A, s1A)
  COMPB(qB, kB, s0B, s1B)
#undef LOADB
#undef COMPB

  // ---- mask + At (causal incl diagonal)
  {
    int col = nw + (lane & 31);
#pragma unroll
    for (int r = 0; r < 16; ++r) {
      int row = mw + (r & 3) + ((r >> 2) << 3) + rbase;
      At[row * 136 + col] = f2b(col <= row ? accS[r] : 0.f);
    }
  }
  __syncthreads();
  // ---- o += At @ vT : wave -> rows [mw,mw+32) x vc [nv,nv+64)
#pragma unroll
  for (int ks = 0; ks < 4; ++ks) {
    bf16x8 a = *(const bf16x8*)(At + (mw + fr) * 136 + ks * 16 + fg);
    bf16x8 b0 = *(const bf16x8*)(vg + (size_t)(nv + fr) * 8192 + ks * 16 + fg);
    bf16x8 b1 = *(const bf16x8*)(vg + (size_t)(nv + 32 + fr) * 8192 + ks * 16 + fg);
    accO0 = __builtin_amdgcn_mfma_f32_32x32x16_bf16(a, b0, accO0, 0, 0, 0);
    accO1 = __builtin_amdgcn_mfma_f32_32x32x16_bf16(a, b1, accO1, 0, 0, 0);
  }
  {
    float* og = o + ((size_t)t0 * 8 + h) * 128;  // row stride 1024
#pragma unroll
    for (int nj = 0; nj < 2; ++nj) {
      const f32x16& acc = nj ? accO1 : accO0;
      int vc = nv + nj * 32 + (lane & 31);
#pragma unroll
      for (int r = 0; r < 16; ++r) {
        int row = mw + (r & 3) + ((r >> 2) << 3) + rbase;
        og[(size_t)row * 1024 + vc] = acc[r];
      }
    }
  }
}

// ---------------------------------------------------------------- rmsnorm (per 1024-dim row)
__global__ __launch_bounds__(256) void rmsnorm_k(const float* __restrict__ o,
                                                 u16* __restrict__ on) {
  __shared__ float red[4];
  int row = blockIdx.x;
  const float* orow = o + (size_t)row * 1024;
  int tid = threadIdx.x;
  float4 v = ((const float4*)orow)[tid];
  float ss = v.x * v.x + v.y * v.y + v.z * v.z + v.w * v.w;
#pragma unroll
  for (int off = 32; off; off >>= 1) ss += __shfl_xor(ss, off, 64);
  if ((tid & 63) == 0) red[tid >> 6] = ss;
  __syncthreads();
  float tot = red[0] + red[1] + red[2] + red[3];
  float rms = rsqrtf(tot * (1.f / 1024.f) + 1e-5f);
  ushort4 r = make_ushort4(f2b(v.x * rms), f2b(v.y * rms), f2b(v.z * rms), f2b(v.w * rms));
  ((ushort4*)(on + (size_t)row * 1024))[tid] = r;
}

// ---------------------------------------------------------------- launch
extern "C" void kernel_launch(void* const* d_in, const int* in_sizes, int n_in,
                              void* d_out, int out_size, void* d_ws, size_t ws_size,
                              hipStream_t stream) {
  const float* x     = (const float*)d_in[0];
  const float* Wq    = (const float*)d_in[1];
  const float* Wk    = (const float*)d_in[2];
  const float* Wv    = (const float*)d_in[3];
  const float* Wo    = (const float*)d_in[4];
  const float* fmq_w = (const float*)d_in[5];
  const float* fmq_b = (const float*)d_in[6];
  const float* fmk_w = (const float*)d_in[7];
  const float* fmk_b = (const float*)d_in[8];

  // Workspace 184 MiB. kvb 64 MiB [0,64MiB) aliases xb[0,16), yb[16,48), onb[48,64).
  // Temporal safety (stream-ordered, per batch): xb dead after vT GEMM (precedes
  // attn_kv64's kv write); yb dead after hedgehog; onb only live rmsnorm->out-GEMM,
  // during which kv is dead (attn_fused64 consumed it); next batch's kv write comes
  // after this batch's out-GEMM.
  char* ws = (char*)d_ws;
  u16*   kvb  = (u16*)(ws + 0);            // 64 MiB (128 chunks x 8 h x 64 KiB)
  u16*   xb   = (u16*)(ws + 0);            // 16 MiB
  u16*   yb   = (u16*)(ws + 16777216);     // 32 MiB (merged q|k, [8192][2048])
  u16*   onb  = (u16*)(ws + 50331648);     // 16 MiB
  u16*   phiq = (u16*)(ws + 67108864);     // 32 MiB
  u16*   phik = (u16*)(ws + 100663296);    // 32 MiB
  u16*   vtb  = (u16*)(ws + 134217728);    // 16 MiB ([1024 vc-rows][8192 t])
  float* obuf = (float*)(ws + 150994944);  // 32 MiB
  u16*   wqkc = (u16*)(ws + 184549376);    // 4 MiB ([2048][1024]: q rows | k rows)
  u16*   wvb  = (u16*)(ws + 188743680);    // 2 MiB
  u16*   wob  = (u16*)(ws + 190840832);    // 2 MiB -> end 192937984 (184 MiB)

  // weight prep (once)
  cast_bf16<<<1024, 256, 0, stream>>>(Wv, wvb, 262144);
  cast_bf16<<<1024, 256, 0, stream>>>(Wo, wob, 262144);
  fold_w<<<1024, 256, 0, stream>>>(Wq, fmq_w, wqkc);
  fold_w<<<1024, 256, 0, stream>>>(Wk, fmk_w, wqkc + 1048576);

  for (int b = 0; b < 2; ++b) {
    const float* xsrc = x + (size_t)b * 8388608;
    float* osrc = (float*)d_out + (size_t)b * 8388608;
    cast_bf16<<<8192, 256, 0, stream>>>(xsrc, xb, 2097152);
    // merged q|k projection: [8192][2048] — 256² 8-phase kernel (32x8 tiles, 256 blocks)
    gemm256<<<256, 512, 0, stream>>>(xb, wqkc, yb, 8192, 2048, 1024, 3);
    hedgehog_sm<<<16384, 256, 0, stream>>>(yb, fmq_b, phiq, 0.0625f, 0);     // 256^-0.5
    hedgehog_sm<<<16384, 256, 0, stream>>>(yb, fmk_b, phik, 1.0f, 1024);
    // v^T via operand swap: C[1024][8192] = Wv @ x^T — gemm_bt, 512 blocks
    gemm_bt<1><<<dim3(64, 8), 256, 0, stream>>>(wvb, xb, vtb, 1024, 8192, 1024, 1, 0);
    // attention, C=64: KV -> exclusive scan -> fused (intra + inter) o
    attn_kv64<<<1024, 256, 0, stream>>>(phik, vtb, kvb);
    kv_scan64<<<256, 256, 0, stream>>>(kvb);
    attn_fused64<<<1024, 256, 0, stream>>>(phiq, phik, vtb, kvb, obuf);
    // rmsnorm + output projection (fp32 out) — gemm_bt, 512 blocks
    rmsnorm_k<<<8192, 256, 0, stream>>>(obuf, onb);
    gemm_bt<0><<<dim3(8, 64), 256, 0, stream>>>(onb, wob, osrc, 8192, 1024, 1024, 0, 3);
  }
}